// Round 1
// baseline (638.691 us; speedup 1.0000x reference)
//
#include <hip/hip_runtime.h>
#include <math.h>

// Problem constants
#define NB          16          // batches
#define NPB         (512*512)   // elements per batch
#define NBINS       64
#define MM_BLOCKS   16          // min/max blocks per batch
#define HB          64          // hist blocks per batch
#define EPSF        1e-8f

// ---------- ordered-uint encoding for float atomic min/max ----------
__device__ __forceinline__ unsigned enc(float f) {
    unsigned u = __float_as_uint(f);
    return (u & 0x80000000u) ? ~u : (u | 0x80000000u);
}
__device__ __forceinline__ float dec(unsigned e) {
    return (e & 0x80000000u) ? __uint_as_float(e & 0x7fffffffu)
                             : __uint_as_float(~e);
}

// ws layout: [0..15] enc-min, [16..31] enc-max (uint), then float hist[2][16][64]
__global__ void init_ws(unsigned* mm, float* hist) {
    int t = threadIdx.x;
    if (t < 16)      mm[t] = 0xFFFFFFFFu;  // min sentinel (atomicMin)
    else if (t < 32) mm[t] = 0u;           // max sentinel (atomicMax)
    for (int i = t; i < 2 * NB * NBINS; i += 256) hist[i] = 0.0f;
}

// ---------- pass 1: per-batch min/max of target ----------
__global__ __launch_bounds__(256) void minmax_k(const float4* __restrict__ tgt,
                                                unsigned* __restrict__ mm) {
    const int batch = blockIdx.x / MM_BLOCKS;
    const int sub   = blockIdx.x % MM_BLOCKS;
    const int F4    = NPB / 4 / MM_BLOCKS;         // float4 per block
    const float4* p = tgt + (size_t)batch * (NPB / 4) + (size_t)sub * F4;

    float mn =  3.4e38f, mx = -3.4e38f;
    for (int i = threadIdx.x; i < F4; i += 256) {
        float4 v = p[i];
        mn = fminf(mn, fminf(fminf(v.x, v.y), fminf(v.z, v.w)));
        mx = fmaxf(mx, fmaxf(fmaxf(v.x, v.y), fmaxf(v.z, v.w)));
    }
    for (int o = 32; o; o >>= 1) {
        mn = fminf(mn, __shfl_down(mn, o));
        mx = fmaxf(mx, __shfl_down(mx, o));
    }
    __shared__ unsigned smn, smx;
    if (threadIdx.x == 0) { smn = 0xFFFFFFFFu; smx = 0u; }
    __syncthreads();
    if ((threadIdx.x & 63) == 0) {
        atomicMin(&smn, enc(mn));
        atomicMax(&smx, enc(mx));
    }
    __syncthreads();
    if (threadIdx.x == 0) {
        atomicMin(&mm[batch],      smn);
        atomicMax(&mm[16 + batch], smx);
    }
}

// ---------- pass 2: windowed soft histogram ----------
// kernel value for bin j at coord u (bin units): exp(-(u-j)^2/2)
// = A * r^k * C[k],  A=exp(-d^2/2), r=exp(d), d=u-j0, j=j0+k, C[k]=exp(-k^2/2)
__device__ __forceinline__ void scatter(float x, float scale, float bias,
                                        float* __restrict__ hcol) {
    float u   = fmaf(x, scale, bias);          // continuous bin coordinate
    float j0f = rintf(u);
    j0f = fminf(fmaxf(j0f, 0.0f), 63.0f);
    int   j0  = (int)j0f;
    float d   = fminf(fmaxf(u - j0f, -20.0f), 20.0f);

    float A  = __expf(-0.5f * d * d);
    float r  = __expf(d);
    float ri = __expf(-d);

    float* hb = hcol + j0 * 64;                // stride 64 floats per bin
    atomicAdd(hb, A);
    float p = A;
    p *= r;  if (j0 + 1 < 64) atomicAdd(hb + 1*64, p * 0.60653066f);
    p *= r;  if (j0 + 2 < 64) atomicAdd(hb + 2*64, p * 0.13533528f);
    p *= r;  if (j0 + 3 < 64) atomicAdd(hb + 3*64, p * 0.011108997f);
    p *= r;  if (j0 + 4 < 64) atomicAdd(hb + 4*64, p * 3.3546263e-4f);
    p *= r;  if (j0 + 5 < 64) atomicAdd(hb + 5*64, p * 3.7266532e-6f);
    p *= r;  if (j0 + 6 < 64) atomicAdd(hb + 6*64, p * 1.5229980e-8f);
    p = A;
    p *= ri; if (j0 - 1 >= 0) atomicAdd(hb - 1*64, p * 0.60653066f);
    p *= ri; if (j0 - 2 >= 0) atomicAdd(hb - 2*64, p * 0.13533528f);
    p *= ri; if (j0 - 3 >= 0) atomicAdd(hb - 3*64, p * 0.011108997f);
    p *= ri; if (j0 - 4 >= 0) atomicAdd(hb - 4*64, p * 3.3546263e-4f);
    p *= ri; if (j0 - 5 >= 0) atomicAdd(hb - 5*64, p * 3.7266532e-6f);
    p *= ri; if (j0 - 6 >= 0) atomicAdd(hb - 6*64, p * 1.5229980e-8f);
}

__global__ __launch_bounds__(256) void hist_k(const float4* __restrict__ pred,
                                              const float4* __restrict__ tgt,
                                              const unsigned* __restrict__ mm,
                                              float* __restrict__ hist) {
    // lds[tensor][bin][lane-column] : column = tid&63 -> bank = lane%32, conflict-free
    __shared__ float lds[2 * NBINS * 64];      // 32 KB
    const int batch = blockIdx.x / HB;
    const int sub   = blockIdx.x % HB;

    for (int i = threadIdx.x; i < 2 * NBINS * 64; i += 256) lds[i] = 0.0f;

    const float vmin  = dec(mm[batch]);
    const float vmax  = dec(mm[16 + batch]);
    const float denom = vmax - vmin + EPSF;
    const float scale = 64.0f / denom;
    const float bias  = fmaf(-vmin, scale, -0.5f);   // u = x*scale + bias
    __syncthreads();

    const int F4 = NPB / 4 / HB;               // 1024 float4 per block
    const size_t base = (size_t)batch * (NPB / 4) + (size_t)sub * F4;
    const int col = threadIdx.x & 63;
    float* h0 = lds + col;                     // pred columns
    float* h1 = lds + NBINS * 64 + col;        // target columns

    for (int i = threadIdx.x; i < F4; i += 256) {
        float4 a = pred[base + i];
        float4 b = tgt[base + i];
        scatter(a.x, scale, bias, h0);  scatter(a.y, scale, bias, h0);
        scatter(a.z, scale, bias, h0);  scatter(a.w, scale, bias, h0);
        scatter(b.x, scale, bias, h1);  scatter(b.y, scale, bias, h1);
        scatter(b.z, scale, bias, h1);  scatter(b.w, scale, bias, h1);
    }
    __syncthreads();

    // reduce 64 lane-columns per (tensor,bin); rotated access -> <=2-way bank alias
    const int t = threadIdx.x;
    if (t < 128) {
        const int tens = t >> 6, bin = t & 63;
        const float* row = lds + (tens * NBINS + bin) * 64;
        float s = 0.0f;
        #pragma unroll
        for (int i = 0; i < 64; i++) s += row[(t + i) & 63];
        atomicAdd(&hist[(tens * NB + batch) * NBINS + bin], s);
    }
}

// ---------- pass 3: KL in fp64 (tiny) ----------
__global__ void final_k(const float* __restrict__ hist, float* __restrict__ out) {
    const int lane = threadIdx.x;              // 64 threads = 64 bins
    double acc = 0.0;
    for (int b = 0; b < NB; b++) {
        double hp = (double)hist[b * NBINS + lane];
        double ht = (double)hist[(NB + b) * NBINS + lane];
        double sp = hp, st = ht;
        for (int o = 32; o; o >>= 1) {
            sp += __shfl_down(sp, o);
            st += __shfl_down(st, o);
        }
        sp = __shfl(sp, 0); st = __shfl(st, 0);
        double pp = hp / (sp + 1e-8);
        double pt = ht / (st + 1e-8);
        double term = pt * (log(pt + 1e-8) - log(pp + 1e-8));
        for (int o = 32; o; o >>= 1) term += __shfl_down(term, o);
        if (lane == 0) acc += term;
    }
    if (lane == 0) out[0] = (float)(0.1 * acc / (double)NB);
}

extern "C" void kernel_launch(void* const* d_in, const int* in_sizes, int n_in,
                              void* d_out, int out_size, void* d_ws, size_t ws_size,
                              hipStream_t stream) {
    const float* pred = (const float*)d_in[0];
    const float* tgt  = (const float*)d_in[1];
    unsigned* mm   = (unsigned*)d_ws;
    float*    hist = (float*)d_ws + 32;
    float*    out  = (float*)d_out;

    init_ws <<<1, 256, 0, stream>>>(mm, hist);
    minmax_k<<<NB * MM_BLOCKS, 256, 0, stream>>>((const float4*)tgt, mm);
    hist_k  <<<NB * HB, 256, 0, stream>>>((const float4*)pred, (const float4*)tgt, mm, hist);
    final_k <<<1, 64, 0, stream>>>(hist, out);
}